// Round 6
// baseline (807.923 us; speedup 1.0000x reference)
//
#include <hip/hip_runtime.h>
#include <hip/hip_bf16.h>
#include <hip/hip_cooperative_groups.h>
#include <stdint.h>

namespace cg = cooperative_groups;

#define HF 256   // H == F == 256
#define GG 50    // G

typedef __attribute__((ext_vector_type(8))) short bf16x8;
typedef __attribute__((ext_vector_type(4))) short bf16x4;
typedef __attribute__((ext_vector_type(4))) float f32x4;

// packed f32x2 -> bf16x2 (v_cvt_pk_bf16_f32 on gfx950), low short = a
__device__ __forceinline__ uint32_t f2bf2u(float a, float b){
    __hip_bfloat162 h = __float22bfloat162_rn(make_float2(a, b));
    union { __hip_bfloat162 h; uint32_t u; } v; v.h = h; return v.u;
}
__device__ __forceinline__ float bf2f(short s){
    union { uint32_t u; float f; } v; v.u = ((uint32_t)(uint16_t)s) << 16;
    return v.f;
}
// shifted softplus
__device__ __forceinline__ float ssp_f(float x){
    return fmaxf(x, 0.f) + __logf(1.f + __expf(-fabsf(x))) - 0.69314718055994531f;
}

struct Params {
    const float *x; const int *eidx; const float *ew; const float *ea;
    const float *w1, *b1, *w2, *b2, *lin1, *lin2, *lin2b;
    float *out;
    float *agg; short *y_p, *x_bf;
    int *cnt, *row, *cursor, *perm, *partial;
    short *w1p, *w2p, *lin1p, *lin2p;
    int N, E, nTiles, eTiles;
};

struct EdgeSmem {
    short smem[21504];     // 43008 B: ea_b[64][72] + hid[64][264]; msgT[256][68] aliases
    int s_e[64], s_i[64], s_j[64];
    float s_c[64];
    unsigned long long bmask;
    int scanbuf[256];
};

// ---------------------------------------------------------------------------
// Weight packing (MFMA B-frag order, 16x16x32 bf16).
// B-frag (ntg, kt): lane l holds B[k=kt*32+(l>>4)*8+j][n=ntg*16+(l&15)].
// pi(s) = (s>>6)*64 + (s&3)*16 + ((s&63)>>2)  (hidden-feature storage perm)
// ---------------------------------------------------------------------------
__device__ __forceinline__ void pack_nat(const float* __restrict__ B,
                                         short* __restrict__ Bp,
                                         int idx, int ktBits, int kmax)
{
    int lane = idx & 63;
    int kt   = (idx >> 6) & ((1 << ktBits) - 1);
    int ntg  = idx >> (6 + ktBits);
    int col  = ntg * 16 + (lane & 15);
    int k0   = kt * 32 + (lane >> 4) * 8;
    uint32_t u[4];
#pragma unroll
    for (int jj = 0; jj < 4; ++jj) {
        int ka = k0 + 2*jj, kb = ka + 1;
        float a = (ka < kmax) ? B[(size_t)ka * HF + col] : 0.f;
        float b = (kb < kmax) ? B[(size_t)kb * HF + col] : 0.f;
        u[jj] = f2bf2u(a, b);
    }
    *(uint4*)&Bp[(size_t)idx * 8] = *(uint4*)u;
}

__device__ __forceinline__ void pack_w2i(const float* __restrict__ w2,
                                         short* __restrict__ w2p, int idx)
{
    int lane = idx & 63;
    int kt   = (idx >> 6) & 7;
    int ntg  = idx >> 9;
    int col  = ntg * 16 + (lane & 15);
    int s0   = kt * 32 + (lane >> 4) * 8;
    uint32_t u[4];
#pragma unroll
    for (int jj = 0; jj < 4; ++jj) {
        int sa = s0 + 2*jj, sb = sa + 1;
        int fa = (sa >> 6) * 64 + (sa & 3) * 16 + ((sa & 63) >> 2);
        int fb = (sb >> 6) * 64 + (sb & 3) * 16 + ((sb & 63) >> 2);
        u[jj] = f2bf2u(w2[(size_t)fa * HF + col], w2[(size_t)fb * HF + col]);
    }
    *(uint4*)&w2p[(size_t)idx * 8] = *(uint4*)u;
}

// phase A work: zero cnt/agg, pack weights, x -> bf16
__device__ __forceinline__ void phaseA(const Params& p, int gtid, int gstr)
{
    for (int i = gtid; i < p.N; i += gstr) p.cnt[i] = 0;
    float4 z = make_float4(0.f, 0.f, 0.f, 0.f);
    int nAgg4 = p.N * (HF / 4);
    for (int i = gtid; i < nAgg4; i += gstr) ((float4*)p.agg)[i] = z;
    for (int i = gtid; i < 2048; i += gstr) pack_nat(p.w1, p.w1p, i, 1, GG);
    for (int i = gtid; i < 8192; i += gstr) pack_w2i(p.w2, p.w2p, i);
    for (int i = gtid; i < 8192; i += gstr) pack_nat(p.lin1, p.lin1p, i, 3, HF);
    for (int i = gtid; i < 8192; i += gstr) pack_nat(p.lin2, p.lin2p, i, 3, HF);
    int nx8 = p.N * (HF / 8);
    for (int i = gtid; i < nx8; i += gstr) {
        const float* xp = p.x + (size_t)i * 8;
        float4 p0 = *(const float4*)(xp);
        float4 p1 = *(const float4*)(xp + 4);
        uint32_t u[4] = { f2bf2u(p0.x, p0.y), f2bf2u(p0.z, p0.w),
                          f2bf2u(p1.x, p1.y), f2bf2u(p1.z, p1.w) };
        *(uint4*)&p.x_bf[(size_t)i * 8] = *(uint4*)u;
    }
}

// ---------------------------------------------------------------------------
// node GEMM tiles (no LDS, 4 independent waves, wave w owns f-slice 64w..)
// ---------------------------------------------------------------------------
__device__ __forceinline__ void node1_tile(const Params& p, int t)
{
    const int tid  = threadIdx.x;
    const int lane = tid & 63, w = tid >> 6, l15 = lane & 15, quad = lane >> 4;
    const int row0 = t * 64;

    f32x4 acc[4][4];
#pragma unroll
    for (int mt = 0; mt < 4; ++mt)
#pragma unroll
        for (int nt = 0; nt < 4; ++nt) acc[mt][nt] = (f32x4){0.f,0.f,0.f,0.f};

#pragma unroll 2
    for (int kt = 0; kt < 8; ++kt) {
        bf16x8 af[4];
#pragma unroll
        for (int mt = 0; mt < 4; ++mt) {
            int r = row0 + mt * 16 + l15;
            int rl = (r < p.N) ? r : 0;
            af[mt] = *(const bf16x8*)&p.x_bf[(size_t)rl * HF + kt * 32 + quad * 8];
        }
#pragma unroll
        for (int nt = 0; nt < 4; ++nt) {
            bf16x8 bfr = *(const bf16x8*)&p.lin1p[(size_t)(((w*4+nt)*8+kt)*64+lane)*8];
#pragma unroll
            for (int mt = 0; mt < 4; ++mt)
                acc[mt][nt] = __builtin_amdgcn_mfma_f32_16x16x32_bf16(af[mt], bfr, acc[mt][nt], 0, 0, 0);
        }
    }
#pragma unroll
    for (int mt = 0; mt < 4; ++mt) {
#pragma unroll
        for (int r = 0; r < 4; ++r) {
            int row = row0 + mt * 16 + quad * 4 + r;
            if (row < p.N) {
                uint2 u = make_uint2(f2bf2u(acc[mt][0][r], acc[mt][1][r]),
                                     f2bf2u(acc[mt][2][r], acc[mt][3][r]));
                *(uint2*)&p.y_p[(size_t)row * HF + w * 64 + l15 * 4] = u;
            }
        }
    }
}

__device__ __forceinline__ void node2_tile(const Params& p, int t)
{
    const int tid  = threadIdx.x;
    const int lane = tid & 63, w = tid >> 6, l15 = lane & 15, quad = lane >> 4;
    const int row0 = t * 64;

    f32x4 acc[4][4];
#pragma unroll
    for (int mt = 0; mt < 4; ++mt)
#pragma unroll
        for (int nt = 0; nt < 4; ++nt) acc[mt][nt] = (f32x4){0.f,0.f,0.f,0.f};

#pragma unroll 2
    for (int kt = 0; kt < 8; ++kt) {
        bf16x8 af[4];
#pragma unroll
        for (int mt = 0; mt < 4; ++mt) {
            int r = row0 + mt * 16 + l15;
            int rl = (r < p.N) ? r : 0;
            const float* ap = p.agg + (size_t)rl * HF + kt * 32 + quad * 8;
            float4 p0 = *(const float4*)(ap);
            float4 p1 = *(const float4*)(ap + 4);
            union { uint32_t u[4]; bf16x8 v; } c;
            c.u[0] = f2bf2u(p0.x, p0.y); c.u[1] = f2bf2u(p0.z, p0.w);
            c.u[2] = f2bf2u(p1.x, p1.y); c.u[3] = f2bf2u(p1.z, p1.w);
            af[mt] = c.v;
        }
#pragma unroll
        for (int nt = 0; nt < 4; ++nt) {
            bf16x8 bfr = *(const bf16x8*)&p.lin2p[(size_t)(((w*4+nt)*8+kt)*64+lane)*8];
#pragma unroll
            for (int mt = 0; mt < 4; ++mt)
                acc[mt][nt] = __builtin_amdgcn_mfma_f32_16x16x32_bf16(af[mt], bfr, acc[mt][nt], 0, 0, 0);
        }
    }
    float bs[4];
#pragma unroll
    for (int nt = 0; nt < 4; ++nt) bs[nt] = p.lin2b[w * 64 + nt * 16 + l15];
#pragma unroll
    for (int mt = 0; mt < 4; ++mt) {
#pragma unroll
        for (int r = 0; r < 4; ++r) {
            int row = row0 + mt * 16 + quad * 4 + r;
            if (row < p.N) {
#pragma unroll
                for (int nt = 0; nt < 4; ++nt) {
                    int f = w * 64 + nt * 16 + l15;
                    float v = ssp_f(acc[mt][nt][r] + bs[nt]) + p.x[(size_t)row * HF + f];
                    p.out[(size_t)row * HF + f] = v;
                }
            }
        }
    }
}

// ---------------------------------------------------------------------------
// edge tile: GEMM1 -> ssp -> GEMM2 -> msg -> segment walk (round-5 structure,
// with w1 B-frags + biases hoisted into registers by the caller)
// ---------------------------------------------------------------------------
__device__ __forceinline__ void edge_tile(EdgeSmem& S, const Params& p, int t,
    const bf16x8 (&w1f)[2][4], const float (&bias1)[4], const float (&bias2)[4])
{
    short* ea_b = S.smem;              // [64][72]
    short* hid  = S.smem + 4608;       // [64][264]
    short* msgT = S.smem;              // [256][68] (aliases, phase 4+)
    const int tid  = threadIdx.x;
    const int lane = tid & 63, w = tid >> 6, l15 = lane & 15, quad = lane >> 4;
    const int e0   = t * 64;

    __syncthreads();   // previous tile's walk fully done before smem reuse

    if (tid < 64) {
        int pp = e0 + tid;
        int e = 0, iv = -1, jv = 0;
        float c = 0.f;
        if (pp < p.E) {
            e  = p.perm[pp];
            iv = p.eidx[e];
            jv = p.eidx[p.E + e];
            float d0 = p.ew[e*3+0], d1 = p.ew[e*3+1], d2 = p.ew[e*3+2];
            float d = sqrtf(d0*d0 + d1*d1 + d2*d2);
            c = (d <= 2.0f) ? 0.5f * (__cosf(d * 1.57079632679489662f) + 1.0f) : 0.f;
        }
        S.s_e[tid] = e; S.s_i[tid] = iv; S.s_j[tid] = jv; S.s_c[tid] = c;
        int ivn = __shfl_down(iv, 1);
        bool flag = (tid == 63) || (iv != ivn);
        unsigned long long m = __ballot(flag);
        if (tid == 0) S.bmask = m;
    }
    __syncthreads();

    // stage edge_attr: float2 loads, pk-convert, dword LDS writes
    for (int idx = tid; idx < 1600; idx += 256) {
        int e = idx / 25, q = idx - e * 25;
        const float* sp = p.ea + (size_t)S.s_e[e] * GG + q * 2;
        float2 v = *(const float2*)sp;
        *(uint32_t*)&ea_b[e * 72 + q * 2] = f2bf2u(v.x, v.y);
    }
    for (int idx = tid; idx < 448; idx += 256) {   // zero-pad k=50..63
        int e = idx / 7, q = idx - e * 7;
        *(uint32_t*)&ea_b[e * 72 + 50 + q * 2] = 0u;
    }
    __syncthreads();

    // GEMM1: [64e x 64k] @ [64k x 64f-slice]
    f32x4 acc1[4][4];
#pragma unroll
    for (int mt = 0; mt < 4; ++mt)
#pragma unroll
        for (int nt = 0; nt < 4; ++nt) acc1[mt][nt] = (f32x4){0.f,0.f,0.f,0.f};

#pragma unroll
    for (int kt = 0; kt < 2; ++kt) {
        bf16x8 af[4];
#pragma unroll
        for (int mt = 0; mt < 4; ++mt)
            af[mt] = *(bf16x8*)&ea_b[(mt * 16 + l15) * 72 + kt * 32 + quad * 8];
#pragma unroll
        for (int nt = 0; nt < 4; ++nt)
#pragma unroll
            for (int mt = 0; mt < 4; ++mt)
                acc1[mt][nt] = __builtin_amdgcn_mfma_f32_16x16x32_bf16(af[mt], w1f[kt][nt], acc1[mt][nt], 0, 0, 0);
    }

    // bias + ssp -> hid (bf16, col' = w*64 + l15*4 + nt)
#pragma unroll
    for (int mt = 0; mt < 4; ++mt) {
#pragma unroll
        for (int r = 0; r < 4; ++r) {
            int e = mt * 16 + quad * 4 + r;
            float v0 = ssp_f(acc1[mt][0][r] + bias1[0]);
            float v1 = ssp_f(acc1[mt][1][r] + bias1[1]);
            float v2 = ssp_f(acc1[mt][2][r] + bias1[2]);
            float v3 = ssp_f(acc1[mt][3][r] + bias1[3]);
            uint2 u = make_uint2(f2bf2u(v0, v1), f2bf2u(v2, v3));
            *(uint2*)&hid[e * 264 + w * 64 + l15 * 4] = u;
        }
    }
    __syncthreads();

    // prefetch y_p rows (overlaps GEMM2 MFMA latency)
    bf16x4 yv[4][4];
#pragma unroll
    for (int mt = 0; mt < 4; ++mt)
#pragma unroll
        for (int r = 0; r < 4; ++r) {
            int e = mt * 16 + quad * 4 + r;
            yv[mt][r] = *(const bf16x4*)&p.y_p[(size_t)S.s_j[e] * HF + w * 64 + l15 * 4];
        }

    // GEMM2: [64e x 256k(perm)] @ [256k x 64f-slice]
    f32x4 acc2[4][4];
#pragma unroll
    for (int mt = 0; mt < 4; ++mt)
#pragma unroll
        for (int nt = 0; nt < 4; ++nt) acc2[mt][nt] = (f32x4){0.f,0.f,0.f,0.f};

#pragma unroll 2
    for (int kt = 0; kt < 8; ++kt) {
        bf16x8 af[4];
#pragma unroll
        for (int mt = 0; mt < 4; ++mt)
            af[mt] = *(bf16x8*)&hid[(mt * 16 + l15) * 264 + kt * 32 + quad * 8];
#pragma unroll
        for (int nt = 0; nt < 4; ++nt) {
            bf16x8 bfr = *(const bf16x8*)&p.w2p[(size_t)(((w*4+nt)*8+kt)*64+lane)*8];
#pragma unroll
            for (int mt = 0; mt < 4; ++mt)
                acc2[mt][nt] = __builtin_amdgcn_mfma_f32_16x16x32_bf16(af[mt], bfr, acc2[mt][nt], 0, 0, 0);
        }
    }
    __syncthreads();   // hid dead; msgT may overwrite

    // msg epilogue -> msgT[col][e] (stride 68: aligned b64/b128)
    float cs[4][4];
#pragma unroll
    for (int mt = 0; mt < 4; ++mt)
#pragma unroll
        for (int r = 0; r < 4; ++r)
            cs[mt][r] = S.s_c[mt * 16 + quad * 4 + r];
#pragma unroll
    for (int mt = 0; mt < 4; ++mt) {
#pragma unroll
        for (int nt = 0; nt < 4; ++nt) {
            int col = w * 64 + nt * 16 + l15;
            float v0 = (acc2[mt][nt][0] + bias2[nt]) * cs[mt][0] * bf2f(yv[mt][0][nt]);
            float v1 = (acc2[mt][nt][1] + bias2[nt]) * cs[mt][1] * bf2f(yv[mt][1][nt]);
            float v2 = (acc2[mt][nt][2] + bias2[nt]) * cs[mt][2] * bf2f(yv[mt][2][nt]);
            float v3 = (acc2[mt][nt][3] + bias2[nt]) * cs[mt][3] * bf2f(yv[mt][3][nt]);
            uint2 u = make_uint2(f2bf2u(v0, v1), f2bf2u(v2, v3));
            *(uint2*)&msgT[col * 68 + mt * 16 + quad * 4] = u;
        }
    }
    __syncthreads();

    // uniform-mask column walk: thread owns col=tid, contiguous e reads
    {
        unsigned long long bm = S.bmask;
        unsigned mlo = __builtin_amdgcn_readfirstlane((unsigned)bm);
        unsigned mhi = __builtin_amdgcn_readfirstlane((unsigned)(bm >> 32));
        const int col = tid;
        float sum = 0.f;
#pragma unroll
        for (int ch = 0; ch < 8; ++ch) {
            bf16x8 v = *(bf16x8*)&msgT[col * 68 + ch * 8];
#pragma unroll
            for (int j = 0; j < 8; ++j) {
                int e = ch * 8 + j;
                sum += bf2f(v[j]);
                unsigned bit = (e < 32) ? ((mlo >> e) & 1u) : ((mhi >> (e - 32)) & 1u);
                if (bit) {
                    int node = __builtin_amdgcn_readfirstlane(S.s_i[e]);
                    if (node >= 0) {
                        int lo = p.row[node], hi = p.row[node + 1];
                        float* ap = p.agg + (size_t)node * HF + col;
                        if (lo >= e0 && hi <= e0 + 64) *ap = sum;
                        else atomicAdd(ap, sum);
                    }
                    sum = 0.f;
                }
            }
        }
    }
}

// hoists + persistent loop over edge tiles
__device__ __forceinline__ void edge_phase(EdgeSmem& S, const Params& p, int stride)
{
    const int tid  = threadIdx.x;
    const int lane = tid & 63, w = tid >> 6, l15 = lane & 15;
    bf16x8 w1f[2][4];
#pragma unroll
    for (int kt = 0; kt < 2; ++kt)
#pragma unroll
        for (int nt = 0; nt < 4; ++nt)
            w1f[kt][nt] = *(const bf16x8*)&p.w1p[(size_t)(((w*4+nt)*2+kt)*64+lane)*8];
    float bias1[4], bias2[4];
#pragma unroll
    for (int nt = 0; nt < 4; ++nt) {
        bias1[nt] = p.b1[w * 64 + nt * 16 + l15];
        bias2[nt] = p.b2[w * 64 + nt * 16 + l15];
    }
    for (int t = blockIdx.x; t < p.eTiles; t += stride)
        edge_tile(S, p, t, w1f, bias1, bias2);
}

// ---------------------------------------------------------------------------
// mega: the whole pipeline in one cooperative launch
// ---------------------------------------------------------------------------
__global__ __launch_bounds__(256, 3)
void mega(Params p)
{
    cg::grid_group grid = cg::this_grid();
    __shared__ EdgeSmem S;
    const int G    = gridDim.x;
    const int tid  = threadIdx.x;
    const int gtid = blockIdx.x * 256 + tid;
    const int gstr = G * 256;

    // A: zero + pack + x conv
    phaseA(p, gtid, gstr);
    grid.sync();

    // B: histogram + node GEMM1 (independent)
    for (int e = gtid; e < p.E; e += gstr) atomicAdd(&p.cnt[p.eidx[e]], 1);
    for (int t = blockIdx.x; t < p.nTiles; t += G) node1_tile(p, t);
    grid.sync();

    // C: per-block partial degree sums
    const int CH = (p.N + G - 1) / G;
    const int lo = blockIdx.x * CH;
    const int hi = min(lo + CH, p.N);
    {
        int s = 0;
        for (int n = lo + tid; n < hi; n += 256) s += p.cnt[n];
        S.scanbuf[tid] = s;
        __syncthreads();
#pragma unroll
        for (int off = 128; off > 0; off >>= 1) {
            if (tid < off) S.scanbuf[tid] += S.scanbuf[tid + off];
            __syncthreads();
        }
        if (tid == 0) p.partial[blockIdx.x] = S.scanbuf[0];
    }
    grid.sync();

    // D: block 0 exclusive-scans partials (G <= 1024)
    if (blockIdx.x == 0) {
        int b4 = tid * 4;
        int a[4]; int ls = 0;
#pragma unroll
        for (int q = 0; q < 4; ++q) { a[q] = (b4 + q < G) ? p.partial[b4 + q] : 0; ls += a[q]; }
        S.scanbuf[tid] = ls;
        __syncthreads();
        for (int off = 1; off < 256; off <<= 1) {
            int v = (tid >= off) ? S.scanbuf[tid - off] : 0;
            __syncthreads();
            S.scanbuf[tid] += v;
            __syncthreads();
        }
        int ex = S.scanbuf[tid] - ls;
#pragma unroll
        for (int q = 0; q < 4; ++q) { if (b4 + q < G) p.partial[b4 + q] = ex; ex += a[q]; }
    }
    grid.sync();

    // E: write row/cursor for this block's chunk (CH <= 256 for G >= 64)
    {
        int c = 0;
        if (lo + tid < hi) c = p.cnt[lo + tid];
        S.scanbuf[tid] = c;
        __syncthreads();
        if (tid == 0) {
            int acc = p.partial[blockIdx.x];
            int m = hi - lo;
            for (int k = 0; k < m; ++k) {
                p.row[lo + k] = acc; p.cursor[lo + k] = acc;
                acc += S.scanbuf[k];
            }
        }
        if (gtid == 0) p.row[p.N] = p.E;
    }
    grid.sync();

    // F: scatter sorted-edge permutation
    for (int e = gtid; e < p.E; e += gstr) {
        int pos = atomicAdd(&p.cursor[p.eidx[e]], 1);
        p.perm[pos] = e;
    }
    grid.sync();

    // G: edge pipeline (persistent)
    edge_phase(S, p, G);
    grid.sync();

    // H: node GEMM2 + ssp + residual
    for (int t = blockIdx.x; t < p.nTiles; t += G) node2_tile(p, t);
}

// ---------------------------------------------------------------------------
// Fallback path (same device code, multi-kernel) if cooperative launch fails
// ---------------------------------------------------------------------------
__global__ __launch_bounds__(256)
void fb_prep(Params p)   // packs + x conv + histogram (cnt pre-zeroed by memset)
{
    const int gtid = blockIdx.x * 256 + threadIdx.x;
    const int gstr = gridDim.x * 256;
    for (int i = gtid; i < 2048; i += gstr) pack_nat(p.w1, p.w1p, i, 1, GG);
    for (int i = gtid; i < 8192; i += gstr) pack_w2i(p.w2, p.w2p, i);
    for (int i = gtid; i < 8192; i += gstr) pack_nat(p.lin1, p.lin1p, i, 3, HF);
    for (int i = gtid; i < 8192; i += gstr) pack_nat(p.lin2, p.lin2p, i, 3, HF);
    int nx8 = p.N * (HF / 8);
    for (int i = gtid; i < nx8; i += gstr) {
        const float* xp = p.x + (size_t)i * 8;
        float4 p0 = *(const float4*)(xp);
        float4 p1 = *(const float4*)(xp + 4);
        uint32_t u[4] = { f2bf2u(p0.x, p0.y), f2bf2u(p0.z, p0.w),
                          f2bf2u(p1.x, p1.y), f2bf2u(p1.z, p1.w) };
        *(uint4*)&p.x_bf[(size_t)i * 8] = *(uint4*)u;
    }
    for (int e = gtid; e < p.E; e += gstr) atomicAdd(&p.cnt[p.eidx[e]], 1);
}

__global__ __launch_bounds__(256)
void fb_scan(Params p)
{
    __shared__ int part[256];
    const int t = threadIdx.x;
    const int CH = (p.N + 255) / 256;
    int lo = t * CH, hi = min(lo + CH, p.N);
    int s = 0;
    for (int n = lo; n < hi; ++n) s += p.cnt[n];
    part[t] = s;
    __syncthreads();
    for (int off = 1; off < 256; off <<= 1) {
        int v = (t >= off) ? part[t - off] : 0;
        __syncthreads();
        part[t] += v;
        __syncthreads();
    }
    int acc = part[t] - s;
    for (int n = lo; n < hi; ++n) {
        p.row[n] = acc; p.cursor[n] = acc;
        acc += p.cnt[n];
    }
    if (t == 255) p.row[p.N] = p.E;
}

__global__ __launch_bounds__(256)
void fb_mid(Params p)   // scatter + node GEMM1
{
    const int gtid = blockIdx.x * 256 + threadIdx.x;
    const int gstr = gridDim.x * 256;
    for (int e = gtid; e < p.E; e += gstr) {
        int pos = atomicAdd(&p.cursor[p.eidx[e]], 1);
        p.perm[pos] = e;
    }
    for (int t = blockIdx.x; t < p.nTiles; t += gridDim.x) node1_tile(p, t);
}

__global__ __launch_bounds__(256, 3)
void fb_edge(Params p)
{
    __shared__ EdgeSmem S;
    edge_phase(S, p, gridDim.x);
}

__global__ __launch_bounds__(256)
void fb_node2(Params p)
{
    for (int t = blockIdx.x; t < p.nTiles; t += gridDim.x) node2_tile(p, t);
}

// ---------------------------------------------------------------------------
extern "C" void kernel_launch(void* const* d_in, const int* in_sizes, int n_in,
                              void* d_out, int out_size, void* d_ws, size_t ws_size,
                              hipStream_t stream)
{
    Params p;
    p.x    = (const float*)d_in[0];
    p.eidx = (const int*)  d_in[1];
    p.ew   = (const float*)d_in[2];
    p.ea   = (const float*)d_in[3];
    p.w1   = (const float*)d_in[4];
    p.b1   = (const float*)d_in[5];
    p.w2   = (const float*)d_in[6];
    p.b2   = (const float*)d_in[7];
    p.lin1 = (const float*)d_in[8];
    p.lin2 = (const float*)d_in[9];
    p.lin2b= (const float*)d_in[10];
    p.out  = (float*)d_out;

    const int N = in_sizes[0] / HF;
    const int E = in_sizes[2] / 3;
    p.N = N; p.E = E;
    p.nTiles = (N + 63) / 64;
    p.eTiles = (E + 63) / 64;

    const size_t fN = (size_t)N * HF;
    p.agg     = (float*)d_ws;
    p.y_p     = (short*)(p.agg + fN);
    p.x_bf    = p.y_p + fN;
    p.cnt     = (int*)(p.x_bf + fN);
    p.row     = p.cnt + N;
    p.cursor  = p.row + (N + 8);
    p.perm    = p.cursor + N;
    p.partial = p.perm + E;
    p.w1p     = (short*)(((uintptr_t)(p.partial + 1040) + 255) & ~(uintptr_t)255);
    p.w2p     = p.w1p + 16384;
    p.lin1p   = p.w2p + 65536;
    p.lin2p   = p.lin1p + 65536;

    // cooperative single-launch path
    int dev = 0; hipGetDevice(&dev);
    int nCU = 0;
    hipDeviceGetAttribute(&nCU, hipDeviceAttributeMultiprocessorCount, dev);
    int maxb = 0;
    hipError_t oe = hipOccupancyMaxActiveBlocksPerMultiprocessor(&maxb, mega, 256, 0);
    int G = (oe == hipSuccess && maxb > 0 && nCU > 0) ? maxb * nCU : 0;
    if (G > 1024) G = 1024;

    bool done = false;
    if (G >= 64) {
        void* args[] = { (void*)&p };
        done = (hipLaunchCooperativeKernel(mega, dim3(G), dim3(256), args, 0, stream)
                == hipSuccess);
    }
    if (!done) {
        hipMemsetAsync(p.cnt, 0, (size_t)N * sizeof(int), stream);
        hipMemsetAsync(p.agg, 0, fN * sizeof(float), stream);
        fb_prep <<<dim3(1024), dim3(256), 0, stream>>>(p);
        fb_scan <<<dim3(1),    dim3(256), 0, stream>>>(p);
        fb_mid  <<<dim3(1024), dim3(256), 0, stream>>>(p);
        fb_edge <<<dim3(p.eTiles), dim3(256), 0, stream>>>(p);
        fb_node2<<<dim3(p.nTiles), dim3(256), 0, stream>>>(p);
    }
}

// Round 7
// 345.892 us; speedup vs baseline: 2.3358x; 2.3358x over previous
//
#include <hip/hip_runtime.h>
#include <hip/hip_bf16.h>
#include <stdint.h>

#define HF 256   // H == F == 256
#define GG 50    // G

typedef __attribute__((ext_vector_type(8))) short bf16x8;
typedef __attribute__((ext_vector_type(4))) short bf16x4;
typedef __attribute__((ext_vector_type(4))) float f32x4;

// packed f32x2 -> bf16x2 (v_cvt_pk_bf16_f32 on gfx950), low short = a
__device__ __forceinline__ uint32_t f2bf2u(float a, float b){
    __hip_bfloat162 h = __float22bfloat162_rn(make_float2(a, b));
    union { __hip_bfloat162 h; uint32_t u; } v; v.h = h; return v.u;
}
__device__ __forceinline__ float bf2f(short s){
    union { uint32_t u; float f; } v; v.u = ((uint32_t)(uint16_t)s) << 16;
    return v.f;
}
// shifted softplus
__device__ __forceinline__ float ssp_f(float x){
    return fmaxf(x, 0.f) + __logf(1.f + __expf(-fabsf(x))) - 0.69314718055994531f;
}

// ---------------------------------------------------------------------------
// prep_kernel: [pack weights] + [x fp32->bf16] + [degree histogram] + [agg=0]
// B-frag (ntg, kt): lane l holds B[k=kt*32+(l>>4)*8+j][n=ntg*16+(l&15)].
// pi(s) = (s>>6)*64 + (s&3)*16 + ((s&63)>>2)  (hidden-feature storage perm)
// ---------------------------------------------------------------------------
__device__ __forceinline__ void pack_natural(const float* __restrict__ B,
                                             short* __restrict__ Bp,
                                             int idx, int KT, int kmax)
{
    int lane = idx & 63;
    int kt   = (idx >> 6) & (KT - 1);
    int ntg  = idx >> (6 + (KT == 2 ? 1 : 3));
    int col  = ntg * 16 + (lane & 15);
    int k0   = kt * 32 + (lane >> 4) * 8;
    uint32_t u[4];
#pragma unroll
    for (int jj = 0; jj < 4; ++jj) {
        int ka = k0 + 2*jj, kb = ka + 1;
        float a = (ka < kmax) ? B[(size_t)ka * HF + col] : 0.f;
        float b = (kb < kmax) ? B[(size_t)kb * HF + col] : 0.f;
        u[jj] = f2bf2u(a, b);
    }
    *(uint4*)&Bp[(size_t)idx * 8] = *(uint4*)u;
}

__global__ __launch_bounds__(256)
void prep_kernel(const float* __restrict__ w1, const float* __restrict__ w2,
                 const float* __restrict__ lin1, const float* __restrict__ lin2,
                 short* __restrict__ w1p, short* __restrict__ w2p,
                 short* __restrict__ lin1p, short* __restrict__ lin2p,
                 const float* __restrict__ x, short* __restrict__ x_bf, int nx8,
                 const int* __restrict__ eidx, int* __restrict__ cnt, int E,
                 float* __restrict__ agg, int nAgg4, int gConv, int gHist)
{
    int b = blockIdx.x, tid = threadIdx.x;
    if (b < 8) {
        pack_natural(w1, w1p, b * 256 + tid, 2, GG);
    } else if (b < 40) {               // w2p: permuted k axis
        int idx = (b - 8) * 256 + tid;
        int lane = idx & 63;
        int kt   = (idx >> 6) & 7;
        int ntg  = idx >> 9;
        int col  = ntg * 16 + (lane & 15);
        int s0   = kt * 32 + (lane >> 4) * 8;
        uint32_t u[4];
#pragma unroll
        for (int jj = 0; jj < 4; ++jj) {
            int sa = s0 + 2*jj, sb = sa + 1;
            int fa = (sa >> 6) * 64 + (sa & 3) * 16 + ((sa & 63) >> 2);
            int fb = (sb >> 6) * 64 + (sb & 3) * 16 + ((sb & 63) >> 2);
            u[jj] = f2bf2u(w2[(size_t)fa * HF + col], w2[(size_t)fb * HF + col]);
        }
        *(uint4*)&w2p[(size_t)idx * 8] = *(uint4*)u;
    } else if (b < 72) {
        pack_natural(lin1, lin1p, (b - 40) * 256 + tid, 8, HF);
    } else if (b < 104) {
        pack_natural(lin2, lin2p, (b - 72) * 256 + tid, 8, HF);
    } else if (b < 104 + gConv) {      // x -> bf16, 8 elems/thread
        int idx = (b - 104) * 256 + tid;
        if (idx < nx8) {
            const float* xp = x + (size_t)idx * 8;
            float4 p0 = *(const float4*)(xp);
            float4 p1 = *(const float4*)(xp + 4);
            uint32_t u[4] = { f2bf2u(p0.x, p0.y), f2bf2u(p0.z, p0.w),
                              f2bf2u(p1.x, p1.y), f2bf2u(p1.z, p1.w) };
            *(uint4*)&x_bf[(size_t)idx * 8] = *(uint4*)u;
        }
    } else if (b < 104 + gConv + gHist) {   // histogram
        int e = (b - 104 - gConv) * 256 + tid;
        if (e < E) atomicAdd(&cnt[eidx[e]], 1);
    } else {                           // agg zero (float4 granular)
        int idx = (b - 104 - gConv - gHist) * 256 + tid;
        if (idx < nAgg4) ((float4*)agg)[idx] = make_float4(0.f, 0.f, 0.f, 0.f);
    }
}

// ---------------------------------------------------------------------------
// scan_kernel: exclusive scan over cnt -> row/cursor (1 block, LDS scan)
// ---------------------------------------------------------------------------
__global__ __launch_bounds__(256)
void scan_kernel(const int* __restrict__ cnt, int* __restrict__ row,
                 int* __restrict__ cursor, int N, int E)
{
    __shared__ int part[256];
    const int t = threadIdx.x;
    const int CH = (N + 255) / 256;
    int lo = t * CH;
    int hi = min(lo + CH, N);
    int s = 0;
    for (int n = lo; n < hi; ++n) s += cnt[n];
    part[t] = s;
    __syncthreads();
    for (int off = 1; off < 256; off <<= 1) {
        int v = (t >= off) ? part[t - off] : 0;
        __syncthreads();
        part[t] += v;
        __syncthreads();
    }
    int acc = part[t] - s;   // exclusive
    for (int n = lo; n < hi; ++n) {
        row[n] = acc; cursor[n] = acc;
        acc += cnt[n];
    }
    if (t == 255) row[N] = E;
}

// ---------------------------------------------------------------------------
// mid_kernel: [scatter perm] + [node GEMM1: y_p = bf16(pi-perm) x@lin1]
// ---------------------------------------------------------------------------
__global__ __launch_bounds__(256)
void mid_kernel(const int* __restrict__ eidx, int* __restrict__ cursor,
                int* __restrict__ perm, int E, int gScatter,
                const short* __restrict__ x_bf, const short* __restrict__ lin1p,
                short* __restrict__ y_p, int N)
{
    const int tid = threadIdx.x;
    if ((int)blockIdx.x < gScatter) {
        int e = blockIdx.x * 256 + tid;
        if (e < E) {
            int pos = atomicAdd(&cursor[eidx[e]], 1);
            perm[pos] = e;
        }
        return;
    }
    const int blk  = blockIdx.x - gScatter;
    const int lane = tid & 63;
    const int w    = tid >> 6;
    const int l15  = lane & 15;
    const int quad = lane >> 4;
    const int row0 = blk * 64;

    f32x4 acc[4][4];
#pragma unroll
    for (int mt = 0; mt < 4; ++mt)
#pragma unroll
        for (int nt = 0; nt < 4; ++nt) acc[mt][nt] = (f32x4){0.f,0.f,0.f,0.f};

#pragma unroll 2
    for (int kt = 0; kt < 8; ++kt) {
        bf16x8 af[4];
#pragma unroll
        for (int mt = 0; mt < 4; ++mt) {
            int r = row0 + mt * 16 + l15;
            int rl = (r < N) ? r : 0;
            af[mt] = *(const bf16x8*)&x_bf[(size_t)rl * HF + kt * 32 + quad * 8];
        }
#pragma unroll
        for (int nt = 0; nt < 4; ++nt) {
            bf16x8 bfr = *(const bf16x8*)&lin1p[(size_t)(((w*4+nt)*8+kt)*64+lane)*8];
#pragma unroll
            for (int mt = 0; mt < 4; ++mt)
                acc[mt][nt] = __builtin_amdgcn_mfma_f32_16x16x32_bf16(af[mt], bfr, acc[mt][nt], 0, 0, 0);
        }
    }
#pragma unroll
    for (int mt = 0; mt < 4; ++mt) {
#pragma unroll
        for (int r = 0; r < 4; ++r) {
            int row = row0 + mt * 16 + quad * 4 + r;
            if (row < N) {
                uint2 u = make_uint2(f2bf2u(acc[mt][0][r], acc[mt][1][r]),
                                     f2bf2u(acc[mt][2][r], acc[mt][3][r]));
                *(uint2*)&y_p[(size_t)row * HF + w * 64 + l15 * 4] = u;
            }
        }
    }
}

// ---------------------------------------------------------------------------
// node2_kernel: out = ssp(agg@lin2 + b) + x
// ---------------------------------------------------------------------------
__global__ __launch_bounds__(256)
void node2_kernel(const float* __restrict__ agg, const short* __restrict__ lin2p,
                  const float* __restrict__ bias, const float* __restrict__ x,
                  float* __restrict__ out, int N)
{
    const int tid  = threadIdx.x;
    const int lane = tid & 63;
    const int w    = tid >> 6;
    const int l15  = lane & 15;
    const int quad = lane >> 4;
    const int row0 = blockIdx.x * 64;

    f32x4 acc[4][4];
#pragma unroll
    for (int mt = 0; mt < 4; ++mt)
#pragma unroll
        for (int nt = 0; nt < 4; ++nt) acc[mt][nt] = (f32x4){0.f,0.f,0.f,0.f};

#pragma unroll 2
    for (int kt = 0; kt < 8; ++kt) {
        bf16x8 af[4];
#pragma unroll
        for (int mt = 0; mt < 4; ++mt) {
            int r = row0 + mt * 16 + l15;
            int rl = (r < N) ? r : 0;
            const float* ap = agg + (size_t)rl * HF + kt * 32 + quad * 8;
            float4 p0 = *(const float4*)(ap);
            float4 p1 = *(const float4*)(ap + 4);
            union { uint32_t u[4]; bf16x8 v; } c;
            c.u[0] = f2bf2u(p0.x, p0.y); c.u[1] = f2bf2u(p0.z, p0.w);
            c.u[2] = f2bf2u(p1.x, p1.y); c.u[3] = f2bf2u(p1.z, p1.w);
            af[mt] = c.v;
        }
#pragma unroll
        for (int nt = 0; nt < 4; ++nt) {
            bf16x8 bfr = *(const bf16x8*)&lin2p[(size_t)(((w*4+nt)*8+kt)*64+lane)*8];
#pragma unroll
            for (int mt = 0; mt < 4; ++mt)
                acc[mt][nt] = __builtin_amdgcn_mfma_f32_16x16x32_bf16(af[mt], bfr, acc[mt][nt], 0, 0, 0);
        }
    }
    float bs[4];
#pragma unroll
    for (int nt = 0; nt < 4; ++nt) bs[nt] = bias[w * 64 + nt * 16 + l15];
#pragma unroll
    for (int mt = 0; mt < 4; ++mt) {
#pragma unroll
        for (int r = 0; r < 4; ++r) {
            int row = row0 + mt * 16 + quad * 4 + r;
            if (row < N) {
#pragma unroll
                for (int nt = 0; nt < 4; ++nt) {
                    int f = w * 64 + nt * 16 + l15;
                    float v = ssp_f(acc[mt][nt][r] + bs[nt]) + x[(size_t)row * HF + f];
                    out[(size_t)row * HF + f] = v;
                }
            }
        }
    }
}

// ---------------------------------------------------------------------------
// edge_mfma: per 64-sorted-edge block, 4 waves, wave w owns f-slice [64w,64w+64)
//   GEMM1: hid = ssp(ea @ w1 + b1)  -> LDS (bf16, pi-permuted cols)
//   GEMM2: W = hid @ w2p; msg = (W+b2)*C*y_p[j] -> msgT[col][e] (LDS, stride 72)
//   GEMM3: segment-sum via 0/1 selection matrix S[run][edge] (MFMA), flush
//          per-run float4 stores (atomics only for tile-boundary runs)
// ---------------------------------------------------------------------------
__global__ __launch_bounds__(256, 3)
void edge_mfma(const float* __restrict__ ea, const int* __restrict__ eidx,
               const float* __restrict__ ew,
               const short* __restrict__ w1p, const float* __restrict__ b1,
               const short* __restrict__ w2p, const float* __restrict__ b2,
               const short* __restrict__ y_p, const int* __restrict__ perm,
               const int* __restrict__ rowp,
               float* __restrict__ agg, int E)
{
    __shared__ short smem[21504];      // 43008 B
    short* ea_b = smem;                // [64][72]   (phase 1-2)
    short* hid  = smem + 4608;         // [64][264]  (phase 2-3)
    short* msgT = smem;                // [256][72]  (phase 4+, aliases; 18432 sh)
    short* St   = smem + 18432;        // [16][64]   (phase 4+, 1024 sh)
    __shared__ int s_e[64], s_i[64], s_j[64];
    __shared__ float s_c[64];
    __shared__ int s_runnode[64];
    __shared__ unsigned char s_runcomp[64];
    __shared__ unsigned long long s_bmask;
    __shared__ int s_runcnt;

    const int tid  = threadIdx.x;
    const int lane = tid & 63;
    const int w    = tid >> 6;
    const int l15  = lane & 15;
    const int quad = lane >> 4;
    const int e0   = blockIdx.x * 64;

    if (tid < 64) {
        int pp = e0 + tid;
        int e = 0, iv = -1, jv = 0;
        float c = 0.f;
        if (pp < E) {
            e  = perm[pp];
            iv = eidx[e];
            jv = eidx[E + e];
            float d0 = ew[e*3+0], d1 = ew[e*3+1], d2 = ew[e*3+2];
            float d = sqrtf(d0*d0 + d1*d1 + d2*d2);
            c = (d <= 2.0f) ? 0.5f * (__cosf(d * 1.57079632679489662f) + 1.0f) : 0.f;
        }
        s_e[tid] = e; s_i[tid] = iv; s_j[tid] = jv; s_c[tid] = c;
        int ivn = __shfl_down(iv, 1);
        bool flag = (tid == 63) || (iv != ivn);     // run ends at tid
        unsigned long long m = __ballot(flag);
        if (flag) {
            int rid = (int)__popcll(m & ((1ull << tid) - 1ull));
            s_runnode[rid] = iv;
            int comp = 0;
            if (iv >= 0) {
                int lo = rowp[iv], hi = rowp[iv + 1];
                comp = (lo >= e0 && hi <= e0 + 64) ? 1 : 0;
            }
            s_runcomp[rid] = (unsigned char)comp;
        }
        if (tid == 0) { s_bmask = m; s_runcnt = (int)__popcll(m); }
    }
    __syncthreads();

    // stage edge_attr: float2 loads, pk-convert, dword LDS writes
    for (int idx = tid; idx < 64 * 25; idx += 256) {
        int e = idx / 25, q = idx - e * 25;
        const float* sp = ea + (size_t)s_e[e] * GG + q * 2;
        float2 v = *(const float2*)sp;
        *(uint32_t*)&ea_b[e * 72 + q * 2] = f2bf2u(v.x, v.y);
    }
    for (int idx = tid; idx < 64 * 7; idx += 256) {   // zero-pad k=50..63
        int e = idx / 7, q = idx - e * 7;
        *(uint32_t*)&ea_b[e * 72 + 50 + q * 2] = 0u;
    }
    __syncthreads();

    // ---- GEMM1: [64e x 64k] @ [64k x 64f-slice]
    f32x4 acc1[4][4];
#pragma unroll
    for (int mt = 0; mt < 4; ++mt)
#pragma unroll
        for (int nt = 0; nt < 4; ++nt) acc1[mt][nt] = (f32x4){0.f,0.f,0.f,0.f};

#pragma unroll
    for (int kt = 0; kt < 2; ++kt) {
        bf16x8 af[4];
#pragma unroll
        for (int mt = 0; mt < 4; ++mt)
            af[mt] = *(bf16x8*)&ea_b[(mt * 16 + l15) * 72 + kt * 32 + quad * 8];
#pragma unroll
        for (int nt = 0; nt < 4; ++nt) {
            bf16x8 bfr = *(const bf16x8*)&w1p[(size_t)(((w*4+nt)*2+kt)*64+lane)*8];
#pragma unroll
            for (int mt = 0; mt < 4; ++mt)
                acc1[mt][nt] = __builtin_amdgcn_mfma_f32_16x16x32_bf16(af[mt], bfr, acc1[mt][nt], 0, 0, 0);
        }
    }

    // bias + ssp -> hid (bf16, col' = w*64 + l15*4 + nt)
    float bias1[4];
#pragma unroll
    for (int nt = 0; nt < 4; ++nt) bias1[nt] = b1[w * 64 + nt * 16 + l15];
#pragma unroll
    for (int mt = 0; mt < 4; ++mt) {
#pragma unroll
        for (int r = 0; r < 4; ++r) {
            int e = mt * 16 + quad * 4 + r;
            float v0 = ssp_f(acc1[mt][0][r] + bias1[0]);
            float v1 = ssp_f(acc1[mt][1][r] + bias1[1]);
            float v2 = ssp_f(acc1[mt][2][r] + bias1[2]);
            float v3 = ssp_f(acc1[mt][3][r] + bias1[3]);
            uint2 u = make_uint2(f2bf2u(v0, v1), f2bf2u(v2, v3));
            *(uint2*)&hid[e * 264 + w * 64 + l15 * 4] = u;
        }
    }
    __syncthreads();

    // ---- prefetch y_p rows (overlaps GEMM2 MFMA latency)
    bf16x4 yv[4][4];
#pragma unroll
    for (int mt = 0; mt < 4; ++mt)
#pragma unroll
        for (int r = 0; r < 4; ++r) {
            int e = mt * 16 + quad * 4 + r;
            yv[mt][r] = *(const bf16x4*)&y_p[(size_t)s_j[e] * HF + w * 64 + l15 * 4];
        }

    // ---- GEMM2: [64e x 256k(perm)] @ [256k x 64f-slice]
    f32x4 acc2[4][4];
#pragma unroll
    for (int mt = 0; mt < 4; ++mt)
#pragma unroll
        for (int nt = 0; nt < 4; ++nt) acc2[mt][nt] = (f32x4){0.f,0.f,0.f,0.f};

#pragma unroll 2
    for (int kt = 0; kt < 8; ++kt) {
        bf16x8 af[4];
#pragma unroll
        for (int mt = 0; mt < 4; ++mt)
            af[mt] = *(bf16x8*)&hid[(mt * 16 + l15) * 264 + kt * 32 + quad * 8];
#pragma unroll
        for (int nt = 0; nt < 4; ++nt) {
            bf16x8 bfr = *(const bf16x8*)&w2p[(size_t)(((w*4+nt)*8+kt)*64+lane)*8];
#pragma unroll
            for (int mt = 0; mt < 4; ++mt)
                acc2[mt][nt] = __builtin_amdgcn_mfma_f32_16x16x32_bf16(af[mt], bfr, acc2[mt][nt], 0, 0, 0);
        }
    }
    __syncthreads();   // hid dead; msgT/St may now overwrite

    // ---- msg epilogue -> msgT[col][e] (stride 72: 16B-aligned rows)
    float bias2[4];
#pragma unroll
    for (int nt = 0; nt < 4; ++nt) bias2[nt] = b2[w * 64 + nt * 16 + l15];
    float cs[4][4];
#pragma unroll
    for (int mt = 0; mt < 4; ++mt)
#pragma unroll
        for (int r = 0; r < 4; ++r)
            cs[mt][r] = s_c[mt * 16 + quad * 4 + r];
#pragma unroll
    for (int mt = 0; mt < 4; ++mt) {
#pragma unroll
        for (int nt = 0; nt < 4; ++nt) {
            int col = w * 64 + nt * 16 + l15;
            float v0 = (acc2[mt][nt][0] + bias2[nt]) * cs[mt][0] * bf2f(yv[mt][0][nt]);
            float v1 = (acc2[mt][nt][1] + bias2[nt]) * cs[mt][1] * bf2f(yv[mt][1][nt]);
            float v2 = (acc2[mt][nt][2] + bias2[nt]) * cs[mt][2] * bf2f(yv[mt][2][nt]);
            float v3 = (acc2[mt][nt][3] + bias2[nt]) * cs[mt][3] * bf2f(yv[mt][3][nt]);
            uint2 u = make_uint2(f2bf2u(v0, v1), f2bf2u(v2, v3));
            *(uint2*)&msgT[col * 72 + mt * 16 + quad * 4] = u;
        }
    }
    // build S^T[run-local][edge] for run group 0 (value 1.0bf where run matches)
    {
        unsigned long long bm = s_bmask;
        int e   = tid & 63;
        int rb  = tid >> 6;
        int rid = (int)__popcll(bm & ((1ull << e) - 1ull));
#pragma unroll
        for (int q = 0; q < 4; ++q) {
            int r = rb + q * 4;
            St[r * 64 + e] = (rid == r) ? (short)0x3F80 : (short)0;
        }
    }
    __syncthreads();

    // ---- GEMM3: O[feature][run] = msgT @ S^T, then flush per run
    const int runcnt = s_runcnt;
    for (int ntg = 0; ntg * 16 < runcnt; ++ntg) {
        if (ntg > 0) {   // rare: >16 runs in a tile
            __syncthreads();
            unsigned long long bm = s_bmask;
            int e   = tid & 63;
            int rb  = tid >> 6;
            int rid = (int)__popcll(bm & ((1ull << e) - 1ull));
#pragma unroll
            for (int q = 0; q < 4; ++q) {
                int r = rb + q * 4;
                St[r * 64 + e] = (rid == ntg * 16 + r) ? (short)0x3F80 : (short)0;
            }
            __syncthreads();
        }
        f32x4 acc3[4];
#pragma unroll
        for (int mt = 0; mt < 4; ++mt) acc3[mt] = (f32x4){0.f,0.f,0.f,0.f};
#pragma unroll
        for (int kt = 0; kt < 2; ++kt) {
            bf16x8 bS = *(bf16x8*)&St[l15 * 64 + kt * 32 + quad * 8];
#pragma unroll
            for (int mt = 0; mt < 4; ++mt) {
                bf16x8 af = *(bf16x8*)&msgT[(w*64 + mt*16 + l15) * 72 + kt*32 + quad*8];
                acc3[mt] = __builtin_amdgcn_mfma_f32_16x16x32_bf16(af, bS, acc3[mt], 0, 0, 0);
            }
        }
        // lane owns run r = ntg*16 + l15; features f = w*64 + mt*16 + quad*4 + g
        int r = ntg * 16 + l15;
        if (r < runcnt) {
            int node = s_runnode[r];
            if (node >= 0) {
                float* ap = agg + (size_t)node * HF + w * 64 + quad * 4;
                if (s_runcomp[r]) {
#pragma unroll
                    for (int mt = 0; mt < 4; ++mt) {
                        float4 v = make_float4(acc3[mt][0], acc3[mt][1], acc3[mt][2], acc3[mt][3]);
                        *(float4*)(ap + mt * 16) = v;
                    }
                } else {
#pragma unroll
                    for (int mt = 0; mt < 4; ++mt)
#pragma unroll
                        for (int g = 0; g < 4; ++g)
                            atomicAdd(ap + mt * 16 + g, acc3[mt][g]);
                }
            }
        }
    }
}

// ---------------------------------------------------------------------------
extern "C" void kernel_launch(void* const* d_in, const int* in_sizes, int n_in,
                              void* d_out, int out_size, void* d_ws, size_t ws_size,
                              hipStream_t stream)
{
    const float* x     = (const float*)d_in[0];
    const int*   eidx  = (const int*)  d_in[1];
    const float* ew    = (const float*)d_in[2];
    const float* ea    = (const float*)d_in[3];
    const float* w1    = (const float*)d_in[4];
    const float* b1    = (const float*)d_in[5];
    const float* w2    = (const float*)d_in[6];
    const float* b2    = (const float*)d_in[7];
    const float* lin1  = (const float*)d_in[8];
    const float* lin2  = (const float*)d_in[9];
    const float* lin2b = (const float*)d_in[10];
    float* out = (float*)d_out;

    const int N = in_sizes[0] / HF;
    const int E = in_sizes[2] / 3;

    const size_t fN = (size_t)N * HF;
    float* agg    = (float*)d_ws;                    // N*256 f32
    short* y_p    = (short*)(agg + fN);              // N*256 bf16 (pi-permuted)
    short* x_bf   = y_p + fN;                        // N*256 bf16
    int*   cnt    = (int*)(x_bf + fN);
    int*   row    = cnt + N;                         // N+1
    int*   cursor = row + (N + 8);
    int*   perm   = cursor + N;
    short* w1p    = (short*)(((uintptr_t)(perm + E) + 255) & ~(uintptr_t)255);
    short* w2p    = w1p + 16384;                     // 32 KB / 128 KB
    short* lin1p  = w2p + 65536;
    short* lin2p  = lin1p + 65536;

    hipMemsetAsync(cnt, 0, (size_t)N * sizeof(int), stream);

    const int nx8   = (int)(fN / 8);
    const int nAgg4 = (int)(fN / 4);
    const int gConv = (nx8 + 255) / 256;
    const int gHist = (E + 255) / 256;
    const int gZero = (nAgg4 + 255) / 256;
    prep_kernel<<<dim3(104 + gConv + gHist + gZero), dim3(256), 0, stream>>>(
        w1, w2, lin1, lin2, w1p, w2p, lin1p, lin2p, x, x_bf, nx8,
        eidx, cnt, E, agg, nAgg4, gConv, gHist);

    scan_kernel<<<dim3(1), dim3(256), 0, stream>>>(cnt, row, cursor, N, E);

    const int gScatter = (E + 255) / 256;
    const int gNode    = (N + 63) / 64;
    mid_kernel<<<dim3(gScatter + gNode), dim3(256), 0, stream>>>(
        eidx, cursor, perm, E, gScatter, x_bf, lin1p, y_p, N);

    edge_mfma<<<dim3((E + 63) / 64), dim3(256), 0, stream>>>(
        ea, eidx, ew, w1p, b1, w2p, b2, y_p, perm, row, agg, E);

    node2_kernel<<<dim3(gNode), dim3(256), 0, stream>>>(
        agg, lin2p, lin2b, x, out, N);
}